// Round 5
// baseline (673.993 us; speedup 1.0000x reference)
//
#include <hip/hip_runtime.h>
#include <stdint.h>

#define TSTEPS 512
#define BATCH  4096
// R5: 256 blocks x 512 threads, 16 rows/block, wave-specialized as R4
// (waves 0-3: hg0+EW0; waves 4-7: xg1+hg1+EW1). The per-step __syncthreads
// is replaced by LDS flag producer/consumer sync: L0 runs up to 2 steps
// ahead of L1 (double-buffer depth), so the two waves sharing a SIMD stall
// at different times and the SIMD stays issuing.
// Flags: f_h0[w] = t after L0 wave w wrote h0(t); f_h1[w] = u after L1 wave
// w wrote h1(u-1); f_rcpt[wv] = iter whose A-fragments wave wv has loaded.
// Writer rule: before overwriting a buffer, all its readers' receipts >= my_iter-1.

typedef __attribute__((ext_vector_type(8))) short bf16x8;
typedef __attribute__((ext_vector_type(4))) float f32x4;
typedef __attribute__((ext_vector_type(2))) float f32x2;

__device__ __forceinline__ short f2bf(float f) {
    uint32_t u = __float_as_uint(f);
    uint32_t r = (u + 0x7fffu + ((u >> 16) & 1u)) >> 16;
    return (short)r;
}
__device__ __forceinline__ float bf2f(short s) {
    return __uint_as_float(((uint32_t)(uint16_t)s) << 16);
}
__device__ __forceinline__ float fast_rcp(float x) { return __builtin_amdgcn_rcpf(x); }
__device__ __forceinline__ float sigmoid_f(float x) { return fast_rcp(1.0f + __expf(-x)); }
__device__ __forceinline__ float tanh_f(float x) { return 1.0f - 2.0f * fast_rcp(1.0f + __expf(2.0f * x)); }

__device__ __forceinline__ void wait4(volatile int* f, int tgt) {
    for (;;) {
        int m0 = f[0], m1 = f[1], m2 = f[2], m3 = f[3];
        if (min(min(m0, m1), min(m2, m3)) >= tgt) return;
        __builtin_amdgcn_s_sleep(1);
    }
}
__device__ __forceinline__ void wait8(volatile int* f, int tgt) {
    for (;;) {
        int m0 = f[0], m1 = f[1], m2 = f[2], m3 = f[3];
        int m4 = f[4], m5 = f[5], m6 = f[6], m7 = f[7];
        int a = min(min(m0, m1), min(m2, m3));
        int b = min(min(m4, m5), min(m6, m7));
        if (min(a, b) >= tgt) return;
        __builtin_amdgcn_s_sleep(1);
    }
}

__global__ __launch_bounds__(512, 2) void gru_fused(
    const float* __restrict__ x,     // [T,B,2]
    const float* __restrict__ Wih0,  // [192,2]
    const float* __restrict__ Whh0,  // [192,64]
    const float* __restrict__ bih0,  // [192]
    const float* __restrict__ bhh0,  // [192]
    const float* __restrict__ Wih1,  // [192,64]
    const float* __restrict__ Whh1,  // [192,64]
    const float* __restrict__ bih1,  // [192]
    const float* __restrict__ bhh1,  // [192]
    const float* __restrict__ Wp,    // [128]
    const float* __restrict__ bp,    // [1]
    float* __restrict__ out)         // [B]
{
    const int tid  = threadIdx.x;
    const int wv   = tid >> 6;      // wave 0..7
    const int isL0 = (wv < 4);
    const int w4   = wv & 3;
    const int l    = tid & 63;
    const int lm   = l & 15;        // A row m / n-col within tile
    const int lq   = l >> 4;        // quad
    const int b0   = blockIdx.x * 16;
    const int j    = w4 * 16 + lm;  // hidden index this lane owns

    __shared__ short h0A[2][16 * 72];
    __shared__ short h1A[2][16 * 72];
    __shared__ float Pf[16][64];
    __shared__ volatile int f_h0[4];    // L0 wave w: last step written
    __shared__ volatile int f_h1[4];    // L1 wave w: iter u after writing h1(u-1)
    __shared__ volatile int f_rcpt[8];  // per wave: last iter whose frags are loaded

    for (int idx = tid; idx < 2 * 16 * 72; idx += 512) {
        ((short*)h0A)[idx] = 0;
        ((short*)h1A)[idx] = 0;
    }
    if (tid < 4)  f_h0[tid] = -1;
    if (tid >= 4 && tid < 8) f_h1[tid - 4] = 0;   // pretend iter-0 writes done
    if (tid < 8)  f_rcpt[tid] = 0;                 // pretend iter-0 frags consumed
    __syncthreads();

    const int aoff = lm * 72 + lq * 8;  // shorts; +32 for K-half 1

    if (isL0) {
        // ================= layer-0 waves: producer =================
        bf16x8 whi[3][2], wlo[3][2];
#pragma unroll
        for (int g = 0; g < 3; ++g) {
            const int row = g * 64 + j;
#pragma unroll
            for (int q = 0; q < 2; ++q) {
                const float* p = Whh0 + row * 64 + q * 32 + lq * 8;
                bf16x8 vh, vl;
#pragma unroll
                for (int i = 0; i < 8; ++i) {
                    float f = p[i];
                    short hs = f2bf(f);
                    vh[i] = hs; vl[i] = f2bf(f - bf2f(hs));
                }
                whi[g][q] = vh; wlo[g][q] = vl;
            }
        }
        const float wi_r0 = Wih0[j * 2 + 0],         wi_r1 = Wih0[j * 2 + 1];
        const float wi_z0 = Wih0[(64 + j) * 2 + 0],  wi_z1 = Wih0[(64 + j) * 2 + 1];
        const float wi_n0 = Wih0[(128 + j) * 2 + 0], wi_n1 = Wih0[(128 + j) * 2 + 1];
        const float br0 = bih0[j] + bhh0[j];
        const float bz0 = bih0[64 + j] + bhh0[64 + j];
        const float bi0_n = bih0[128 + j], bh0_n = bhh0[128 + j];

        float h0r[4] = {0.f, 0.f, 0.f, 0.f};
        f32x2 xc[4], xnb[4];
#pragma unroll
        for (int i = 0; i < 4; ++i)
            xc[i] = *(const f32x2*)(x + (size_t)(b0 + lq * 4 + i) * 2);

        for (int t = 0; t < TSTEPS; ++t) {
            const int pr = t & 1, pw = pr ^ 1;

            // h0A[pr] (= h0(t-1)) ready? (self trivially >= t-1)
            if (t > 0) wait4(f_h0, t - 1);
            bf16x8 a00 = *(const bf16x8*)&h0A[pr][aoff];
            bf16x8 a01 = *(const bf16x8*)&h0A[pr][aoff + 32];
            __threadfence_block();           // frag reads complete
            if (l == 0) f_rcpt[wv] = t;      // receipt: consumed h0(t-1)

            const int tn = (t + 1) & (TSTEPS - 1);
#pragma unroll
            for (int i = 0; i < 4; ++i)
                xnb[i] = *(const f32x2*)(x + (size_t)(tn * BATCH + b0 + lq * 4 + i) * 2);

            f32x4 hg0[3];
#pragma unroll
            for (int g = 0; g < 3; ++g) {
                const f32x4 z4 = {0.f, 0.f, 0.f, 0.f};
                f32x4 c;
                c = __builtin_amdgcn_mfma_f32_16x16x32_bf16(a00, whi[g][0], z4, 0, 0, 0);
                c = __builtin_amdgcn_mfma_f32_16x16x32_bf16(a01, whi[g][1], c, 0, 0, 0);
                c = __builtin_amdgcn_mfma_f32_16x16x32_bf16(a00, wlo[g][0], c, 0, 0, 0);
                hg0[g] = __builtin_amdgcn_mfma_f32_16x16x32_bf16(a01, wlo[g][1], c, 0, 0, 0);
            }

            float hnew[4];
#pragma unroll
            for (int i = 0; i < 4; ++i) {
                const float x0 = xc[i].x, x1 = xc[i].y;
                const float gr = fmaf(wi_r0, x0, fmaf(wi_r1, x1, br0 + hg0[0][i]));
                const float gz = fmaf(wi_z0, x0, fmaf(wi_z1, x1, bz0 + hg0[1][i]));
                const float hn = hg0[2][i] + bh0_n;
                const float gn = fmaf(wi_n0, x0, fmaf(wi_n1, x1, bi0_n));
                const float r = sigmoid_f(gr);
                const float z = sigmoid_f(gz);
                const float n = tanh_f(fmaf(r, hn, gn));
                const float h = fmaf(z, h0r[i] - n, n);
                h0r[i] = h;
                hnew[i] = h;
            }

            // before overwriting h0A[pw] (holds h0(t-2)), all readers done with it:
            wait8((volatile int*)f_rcpt, t - 1);
#pragma unroll
            for (int i = 0; i < 4; ++i)
                h0A[pw][(lq * 4 + i) * 72 + j] = f2bf(hnew[i]);
            __threadfence_block();           // data visible before flag
            if (l == 0) f_h0[w4] = t;

#pragma unroll
            for (int i = 0; i < 4; ++i) xc[i] = xnb[i];
        }

        const float wp0 = Wp[j];
#pragma unroll
        for (int i = 0; i < 4; ++i)
            Pf[lq * 4 + i][j] = wp0 * h0r[i];
        __syncthreads();       // epilogue barrier #1
        __syncthreads();       // epilogue barrier #2
    } else {
        // ================= layer-1 waves: consumer =================
        bf16x8 w1hi[3][2], w1lo[3][2], w2hi[3][2], w2lo[3][2];
#pragma unroll
        for (int g = 0; g < 3; ++g) {
            const int row = g * 64 + j;
#pragma unroll
            for (int q = 0; q < 2; ++q) {
                const float* p1 = Wih1 + row * 64 + q * 32 + lq * 8;
                const float* p2 = Whh1 + row * 64 + q * 32 + lq * 8;
                bf16x8 v1h, v1l, v2h, v2l;
#pragma unroll
                for (int i = 0; i < 8; ++i) {
                    float f1 = p1[i], f2 = p2[i];
                    short s1 = f2bf(f1), s2 = f2bf(f2);
                    v1h[i] = s1; v1l[i] = f2bf(f1 - bf2f(s1));
                    v2h[i] = s2; v2l[i] = f2bf(f2 - bf2f(s2));
                }
                w1hi[g][q] = v1h; w1lo[g][q] = v1l;
                w2hi[g][q] = v2h; w2lo[g][q] = v2l;
            }
        }
        const float br1 = bih1[j] + bhh1[j];
        const float bz1 = bih1[64 + j] + bhh1[64 + j];
        const float bi1_n = bih1[128 + j], bh1_n = bhh1[128 + j];

        float h1r[4] = {0.f, 0.f, 0.f, 0.f};

        for (int u = 1; u <= TSTEPS; ++u) {
            const int pr = u & 1, pw = pr ^ 1;

            // need h0(u-1) (f_h0 >= u-1) and peers' h1(u-2) writes (f_h1 >= u-1)
            wait4(f_h0, u - 1);
            wait4(f_h1, u - 1);
            bf16x8 a00 = *(const bf16x8*)&h0A[pr][aoff];
            bf16x8 a01 = *(const bf16x8*)&h0A[pr][aoff + 32];
            bf16x8 a10 = *(const bf16x8*)&h1A[pr][aoff];
            bf16x8 a11 = *(const bf16x8*)&h1A[pr][aoff + 32];
            __threadfence_block();
            if (l == 0) f_rcpt[wv] = u;

            f32x4 xg1[3], hg1[3];
#pragma unroll
            for (int g = 0; g < 3; ++g) {
                const f32x4 z4 = {0.f, 0.f, 0.f, 0.f};
                f32x4 d;
                d = __builtin_amdgcn_mfma_f32_16x16x32_bf16(a00, w1hi[g][0], z4, 0, 0, 0);
                d = __builtin_amdgcn_mfma_f32_16x16x32_bf16(a01, w1hi[g][1], d, 0, 0, 0);
                d = __builtin_amdgcn_mfma_f32_16x16x32_bf16(a00, w1lo[g][0], d, 0, 0, 0);
                xg1[g] = __builtin_amdgcn_mfma_f32_16x16x32_bf16(a01, w1lo[g][1], d, 0, 0, 0);
                f32x4 e;
                e = __builtin_amdgcn_mfma_f32_16x16x32_bf16(a10, w2hi[g][0], z4, 0, 0, 0);
                e = __builtin_amdgcn_mfma_f32_16x16x32_bf16(a11, w2hi[g][1], e, 0, 0, 0);
                e = __builtin_amdgcn_mfma_f32_16x16x32_bf16(a10, w2lo[g][0], e, 0, 0, 0);
                hg1[g] = __builtin_amdgcn_mfma_f32_16x16x32_bf16(a11, w2lo[g][1], e, 0, 0, 0);
            }

            float hnew[4];
#pragma unroll
            for (int i = 0; i < 4; ++i) {
                const float r = sigmoid_f(xg1[0][i] + br1 + hg1[0][i]);
                const float z = sigmoid_f(xg1[1][i] + bz1 + hg1[1][i]);
                const float n = tanh_f(fmaf(r, hg1[2][i] + bh1_n, xg1[2][i] + bi1_n));
                const float h = fmaf(z, h1r[i] - n, n);
                h1r[i] = h;
                hnew[i] = h;
            }

            // before overwriting h1A[pw] (holds h1(u-3)): L1 peers' receipts >= u-1
            wait4((volatile int*)&f_rcpt[4], u - 1);
#pragma unroll
            for (int i = 0; i < 4; ++i)
                h1A[pw][(lq * 4 + i) * 72 + j] = f2bf(hnew[i]);
            __threadfence_block();
            if (l == 0) f_h1[w4] = u;
        }

        __syncthreads();       // epilogue barrier #1 (Pf written by L0)
        const float wp1 = Wp[64 + j];
#pragma unroll
        for (int i = 0; i < 4; ++i)
            Pf[lq * 4 + i][j] += wp1 * h1r[i];
        __syncthreads();       // epilogue barrier #2
    }

    // ---- final reduce: out[b] = sum_j Pf[row][j] + bp ----
    if (tid < 16) {
        float s = bp[0];
#pragma unroll 8
        for (int k = 0; k < 64; ++k) s += Pf[tid][k];
        out[b0 + tid] = s;
    }
}

extern "C" void kernel_launch(void* const* d_in, const int* in_sizes, int n_in,
                              void* d_out, int out_size, void* d_ws, size_t ws_size,
                              hipStream_t stream) {
    (void)in_sizes; (void)n_in; (void)out_size; (void)d_ws; (void)ws_size;
    gru_fused<<<dim3(BATCH / 16), dim3(512), 0, stream>>>(
        (const float*)d_in[0], (const float*)d_in[1], (const float*)d_in[2],
        (const float*)d_in[3], (const float*)d_in[4], (const float*)d_in[5],
        (const float*)d_in[6], (const float*)d_in[7], (const float*)d_in[8],
        (const float*)d_in[9], (const float*)d_in[10], (float*)d_out);
}

// Round 6
// 597.738 us; speedup vs baseline: 1.1276x; 1.1276x over previous
//
#include <hip/hip_runtime.h>
#include <stdint.h>

#define TSTEPS 512
#define BATCH  4096
// R6: 512 blocks x 512 threads, 8 batch rows/block (M=16 MFMA, valid rows at
// m&3 in {0,1}) -> 2 independent blocks/CU, 4 waves/SIMD. Wave-specialized as
// R4 (waves 0-3: hg0+EW0, waves 4-7: xg1+hg1+EW1), plain __syncthreads (R5's
// flag sync regressed). exp2 prescaling folded into weights/biases: r,z rows
// x -log2e, n rows x 2*log2e, so sigmoid/tanh = rcp(1+exp2(x)) with no muls.
// VGPR must stay <=128 for 4 waves/EU (R4 measured 116; watch WRITE_SIZE for
// the R3 spill signature).

typedef __attribute__((ext_vector_type(8))) short bf16x8;
typedef __attribute__((ext_vector_type(4))) float f32x4;
typedef __attribute__((ext_vector_type(2))) float f32x2;

#define SRZ (-1.4426950408889634f)   /* -log2(e): r,z gates */
#define SN  ( 2.8853900817779268f)   /* 2*log2(e): n gate   */

__device__ __forceinline__ short f2bf(float f) {
    uint32_t u = __float_as_uint(f);
    uint32_t r = (u + 0x7fffu + ((u >> 16) & 1u)) >> 16;
    return (short)r;
}
__device__ __forceinline__ float bf2f(short s) {
    return __uint_as_float(((uint32_t)(uint16_t)s) << 16);
}
__device__ __forceinline__ float fast_rcp(float x) { return __builtin_amdgcn_rcpf(x); }
#if __has_builtin(__builtin_amdgcn_exp2f)
__device__ __forceinline__ float exp2_fast(float x) { return __builtin_amdgcn_exp2f(x); }
#else
__device__ __forceinline__ float exp2_fast(float x) { return __expf(x * 0.6931471805599453f); }
#endif
// inputs arrive pre-scaled: sigmoid(g) = rcp(1+exp2(-log2e*g)); tanh via 2*log2e
__device__ __forceinline__ float sig_pre(float y) { return fast_rcp(1.0f + exp2_fast(y)); }
__device__ __forceinline__ float tanh_pre(float y) { return 1.0f - 2.0f * fast_rcp(1.0f + exp2_fast(y)); }

__global__ __launch_bounds__(512, 4) void gru_fused(
    const float* __restrict__ x,     // [T,B,2]
    const float* __restrict__ Wih0,  // [192,2]
    const float* __restrict__ Whh0,  // [192,64]
    const float* __restrict__ bih0,  // [192]
    const float* __restrict__ bhh0,  // [192]
    const float* __restrict__ Wih1,  // [192,64]
    const float* __restrict__ Whh1,  // [192,64]
    const float* __restrict__ bih1,  // [192]
    const float* __restrict__ bhh1,  // [192]
    const float* __restrict__ Wp,    // [128]
    const float* __restrict__ bp,    // [1]
    float* __restrict__ out)         // [B]
{
    const int tid  = threadIdx.x;
    const int wv   = tid >> 6;      // wave 0..7
    const int isL0 = (wv < 4);
    const int w4   = wv & 3;
    const int l    = tid & 63;
    const int lm   = l & 15;        // A row m / n-col within tile
    const int lq   = l >> 4;        // quad
    const int b0   = blockIdx.x * 8;
    const int j    = w4 * 16 + lm;  // hidden index this lane owns

    // Batch row r (0..7) lives at MFMA row m = lq*4 + i (r = lq*2+i, i in {0,1});
    // rows with m&3 >= 2 stay zero forever (zeroed once, never written).
    __shared__ short h0A[2][16 * 72];
    __shared__ short h1A[2][16 * 72];
    __shared__ float Pf[8][64];

    for (int idx = tid; idx < 2 * 16 * 72; idx += 512) {
        ((short*)h0A)[idx] = 0;
        ((short*)h1A)[idx] = 0;
    }
    __syncthreads();

    const int aoff = lm * 72 + lq * 8;  // shorts; +32 for K-half 1

    if (isL0) {
        // ================= layer-0 waves =================
        // Whh0 B-fragments, gate-prescaled, hi/lo bf16 split.
        bf16x8 whi[3][2], wlo[3][2];
#pragma unroll
        for (int g = 0; g < 3; ++g) {
            const int row = g * 64 + j;
            const float sc = (g == 2) ? SN : SRZ;
#pragma unroll
            for (int q = 0; q < 2; ++q) {
                const float* p = Whh0 + row * 64 + q * 32 + lq * 8;
                bf16x8 vh, vl;
#pragma unroll
                for (int i = 0; i < 8; ++i) {
                    float f = p[i] * sc;
                    short hs = f2bf(f);
                    vh[i] = hs; vl[i] = f2bf(f - bf2f(hs));
                }
                whi[g][q] = vh; wlo[g][q] = vl;
            }
        }
        const float wi_r0 = SRZ * Wih0[j * 2 + 0],         wi_r1 = SRZ * Wih0[j * 2 + 1];
        const float wi_z0 = SRZ * Wih0[(64 + j) * 2 + 0],  wi_z1 = SRZ * Wih0[(64 + j) * 2 + 1];
        const float wi_n0 = SN  * Wih0[(128 + j) * 2 + 0], wi_n1 = SN  * Wih0[(128 + j) * 2 + 1];
        const float br0 = SRZ * (bih0[j] + bhh0[j]);
        const float bz0 = SRZ * (bih0[64 + j] + bhh0[64 + j]);
        const float bi0_n = SN * bih0[128 + j], bh0_n = SN * bhh0[128 + j];

        float h0r[2] = {0.f, 0.f};
        f32x2 xc[2], xnb[2];
#pragma unroll
        for (int i = 0; i < 2; ++i)
            xc[i] = *(const f32x2*)(x + (size_t)(b0 + lq * 2 + i) * 2);

        for (int t = 0; t <= TSTEPS; ++t) {
            const int pr = t & 1, pw = pr ^ 1;
            bf16x8 a00 = *(const bf16x8*)&h0A[pr][aoff];
            bf16x8 a01 = *(const bf16x8*)&h0A[pr][aoff + 32];

            const int tn = (t + 1) & (TSTEPS - 1);
#pragma unroll
            for (int i = 0; i < 2; ++i)
                xnb[i] = *(const f32x2*)(x + (size_t)(tn * BATCH + b0 + lq * 2 + i) * 2);

            f32x4 hg0[3];
#pragma unroll
            for (int g = 0; g < 3; ++g) {
                const f32x4 z4 = {0.f, 0.f, 0.f, 0.f};
                f32x4 c;
                c = __builtin_amdgcn_mfma_f32_16x16x32_bf16(a00, whi[g][0], z4, 0, 0, 0);
                c = __builtin_amdgcn_mfma_f32_16x16x32_bf16(a01, whi[g][1], c, 0, 0, 0);
                c = __builtin_amdgcn_mfma_f32_16x16x32_bf16(a00, wlo[g][0], c, 0, 0, 0);
                hg0[g] = __builtin_amdgcn_mfma_f32_16x16x32_bf16(a01, wlo[g][1], c, 0, 0, 0);
            }

            if (t < TSTEPS) {
#pragma unroll
                for (int i = 0; i < 2; ++i) {
                    const float x0 = xc[i].x, x1 = xc[i].y;
                    const float gr = fmaf(wi_r0, x0, fmaf(wi_r1, x1, br0 + hg0[0][i]));
                    const float gz = fmaf(wi_z0, x0, fmaf(wi_z1, x1, bz0 + hg0[1][i]));
                    const float hn = hg0[2][i] + bh0_n;
                    const float gn = fmaf(wi_n0, x0, fmaf(wi_n1, x1, bi0_n));
                    const float r = sig_pre(gr);
                    const float z = sig_pre(gz);
                    const float n = tanh_pre(fmaf(r, hn, gn));
                    const float h = fmaf(z, h0r[i] - n, n);
                    h0r[i] = h;
                    h0A[pw][(lq * 4 + i) * 72 + j] = f2bf(h);
                }
            }
#pragma unroll
            for (int i = 0; i < 2; ++i) xc[i] = xnb[i];
            __syncthreads();   // barrier 1..513
        }

        const float wp0 = Wp[j];
#pragma unroll
        for (int i = 0; i < 2; ++i)
            Pf[lq * 2 + i][j] = wp0 * h0r[i];
        __syncthreads();       // barrier 514
        __syncthreads();       // barrier 515
    } else {
        // ================= layer-1 waves =================
        bf16x8 w1hi[3][2], w1lo[3][2], w2hi[3][2], w2lo[3][2];
#pragma unroll
        for (int g = 0; g < 3; ++g) {
            const int row = g * 64 + j;
            const float sc = (g == 2) ? SN : SRZ;
#pragma unroll
            for (int q = 0; q < 2; ++q) {
                const float* p1 = Wih1 + row * 64 + q * 32 + lq * 8;
                const float* p2 = Whh1 + row * 64 + q * 32 + lq * 8;
                bf16x8 v1h, v1l, v2h, v2l;
#pragma unroll
                for (int i = 0; i < 8; ++i) {
                    float f1 = p1[i] * sc, f2 = p2[i] * sc;
                    short s1 = f2bf(f1), s2 = f2bf(f2);
                    v1h[i] = s1; v1l[i] = f2bf(f1 - bf2f(s1));
                    v2h[i] = s2; v2l[i] = f2bf(f2 - bf2f(s2));
                }
                w1hi[g][q] = v1h; w1lo[g][q] = v1l;
                w2hi[g][q] = v2h; w2lo[g][q] = v2l;
            }
        }
        const float br1 = SRZ * (bih1[j] + bhh1[j]);
        const float bz1 = SRZ * (bih1[64 + j] + bhh1[64 + j]);
        const float bi1_n = SN * bih1[128 + j], bh1_n = SN * bhh1[128 + j];

        float h1r[2] = {0.f, 0.f};

        for (int t = 0; t <= TSTEPS; ++t) {
            const int pr = t & 1, pw = pr ^ 1;
            bf16x8 a00 = *(const bf16x8*)&h0A[pr][aoff];
            bf16x8 a01 = *(const bf16x8*)&h0A[pr][aoff + 32];
            bf16x8 a10 = *(const bf16x8*)&h1A[pr][aoff];
            bf16x8 a11 = *(const bf16x8*)&h1A[pr][aoff + 32];

            f32x4 xg1[3], hg1[3];
#pragma unroll
            for (int g = 0; g < 3; ++g) {
                const f32x4 z4 = {0.f, 0.f, 0.f, 0.f};
                f32x4 d;
                d = __builtin_amdgcn_mfma_f32_16x16x32_bf16(a00, w1hi[g][0], z4, 0, 0, 0);
                d = __builtin_amdgcn_mfma_f32_16x16x32_bf16(a01, w1hi[g][1], d, 0, 0, 0);
                d = __builtin_amdgcn_mfma_f32_16x16x32_bf16(a00, w1lo[g][0], d, 0, 0, 0);
                xg1[g] = __builtin_amdgcn_mfma_f32_16x16x32_bf16(a01, w1lo[g][1], d, 0, 0, 0);
                f32x4 e;
                e = __builtin_amdgcn_mfma_f32_16x16x32_bf16(a10, w2hi[g][0], z4, 0, 0, 0);
                e = __builtin_amdgcn_mfma_f32_16x16x32_bf16(a11, w2hi[g][1], e, 0, 0, 0);
                e = __builtin_amdgcn_mfma_f32_16x16x32_bf16(a10, w2lo[g][0], e, 0, 0, 0);
                hg1[g] = __builtin_amdgcn_mfma_f32_16x16x32_bf16(a11, w2lo[g][1], e, 0, 0, 0);
            }

            if (t > 0) {
#pragma unroll
                for (int i = 0; i < 2; ++i) {
                    const float r = sig_pre(xg1[0][i] + br1 + hg1[0][i]);
                    const float z = sig_pre(xg1[1][i] + bz1 + hg1[1][i]);
                    const float n = tanh_pre(fmaf(r, hg1[2][i] + bh1_n, xg1[2][i] + bi1_n));
                    const float h = fmaf(z, h1r[i] - n, n);
                    h1r[i] = h;
                    h1A[pw][(lq * 4 + i) * 72 + j] = f2bf(h);
                }
            }
            __syncthreads();   // barrier 1..513
        }

        __syncthreads();       // barrier 514 (Pf written by L0 waves)
        const float wp1 = Wp[64 + j];
#pragma unroll
        for (int i = 0; i < 2; ++i)
            Pf[lq * 2 + i][j] += wp1 * h1r[i];
        __syncthreads();       // barrier 515
    }

    // ---- final reduce: out[b] = sum_j Pf[row][j] + bp ----
    if (tid < 8) {
        float s = bp[0];
#pragma unroll 8
        for (int k = 0; k < 64; ++k) s += Pf[tid][k];
        out[b0 + tid] = s;
    }
}

extern "C" void kernel_launch(void* const* d_in, const int* in_sizes, int n_in,
                              void* d_out, int out_size, void* d_ws, size_t ws_size,
                              hipStream_t stream) {
    (void)in_sizes; (void)n_in; (void)out_size; (void)d_ws; (void)ws_size;
    gru_fused<<<dim3(BATCH / 8), dim3(512), 0, stream>>>(
        (const float*)d_in[0], (const float*)d_in[1], (const float*)d_in[2],
        (const float*)d_in[3], (const float*)d_in[4], (const float*)d_in[5],
        (const float*)d_in[6], (const float*)d_in[7], (const float*)d_in[8],
        (const float*)d_in[9], (const float*)d_in[10], (float*)d_out);
}

// Round 7
// 571.963 us; speedup vs baseline: 1.1784x; 1.0451x over previous
//
#include <hip/hip_runtime.h>
#include <stdint.h>

#define TSTEPS 512
#define BATCH  4096
// R7 = R6 grid (512 blocks x 8 rows -> 2 blocks/CU) + R4 launch bounds
// (512,2): allocator keeps ~116 VGPR (no spill; (512,4) capped to 64 and
// spilled 68 MB/step -- R6 regression), HW still co-resides 2 blocks/CU since
// 116 <= 128. Wave-specialized (waves 0-3: hg0+EW0, waves 4-7: xg1+hg1+EW1),
// one __syncthreads per step. Gate biases folded into MFMA accumulator init;
// x loaded as one f32x4 per lane per step; exp2 prescale folded into weights.

typedef __attribute__((ext_vector_type(8))) short bf16x8;
typedef __attribute__((ext_vector_type(4))) float f32x4;

#define SRZ (-1.4426950408889634f)   /* -log2(e): r,z gates */
#define SN  ( 2.8853900817779268f)   /* 2*log2(e): n gate   */

__device__ __forceinline__ short f2bf(float f) {
    uint32_t u = __float_as_uint(f);
    uint32_t r = (u + 0x7fffu + ((u >> 16) & 1u)) >> 16;
    return (short)r;
}
__device__ __forceinline__ float bf2f(short s) {
    return __uint_as_float(((uint32_t)(uint16_t)s) << 16);
}
__device__ __forceinline__ float fast_rcp(float x) { return __builtin_amdgcn_rcpf(x); }
#if __has_builtin(__builtin_amdgcn_exp2f)
__device__ __forceinline__ float exp2_fast(float x) { return __builtin_amdgcn_exp2f(x); }
#else
__device__ __forceinline__ float exp2_fast(float x) { return __expf(x * 0.6931471805599453f); }
#endif
__device__ __forceinline__ float sig_pre(float y) { return fast_rcp(1.0f + exp2_fast(y)); }
__device__ __forceinline__ float tanh_pre(float y) { return 1.0f - 2.0f * fast_rcp(1.0f + exp2_fast(y)); }

__global__ __launch_bounds__(512, 2) void gru_fused(
    const float* __restrict__ x,     // [T,B,2]
    const float* __restrict__ Wih0,  // [192,2]
    const float* __restrict__ Whh0,  // [192,64]
    const float* __restrict__ bih0,  // [192]
    const float* __restrict__ bhh0,  // [192]
    const float* __restrict__ Wih1,  // [192,64]
    const float* __restrict__ Whh1,  // [192,64]
    const float* __restrict__ bih1,  // [192]
    const float* __restrict__ bhh1,  // [192]
    const float* __restrict__ Wp,    // [128]
    const float* __restrict__ bp,    // [1]
    float* __restrict__ out)         // [B]
{
    const int tid  = threadIdx.x;
    const int wv   = tid >> 6;      // wave 0..7
    const int isL0 = (wv < 4);
    const int w4   = wv & 3;
    const int l    = tid & 63;
    const int lm   = l & 15;        // A row m / n-col within tile
    const int lq   = l >> 4;        // quad
    const int b0   = blockIdx.x * 8;
    const int j    = w4 * 16 + lm;  // hidden index this lane owns

    // Batch row r (0..7) at MFMA row m = lq*4 + i (r = lq*2+i, i in {0,1});
    // rows with m&3 >= 2 stay zero forever.
    __shared__ short h0A[2][16 * 72];
    __shared__ short h1A[2][16 * 72];
    __shared__ float Pf[8][64];

    for (int idx = tid; idx < 2 * 16 * 72; idx += 512) {
        ((short*)h0A)[idx] = 0;
        ((short*)h1A)[idx] = 0;
    }
    __syncthreads();

    const int aoff = lm * 72 + lq * 8;  // shorts; +32 for K-half 1

    if (isL0) {
        // ================= layer-0 waves =================
        bf16x8 whi[3][2], wlo[3][2];
#pragma unroll
        for (int g = 0; g < 3; ++g) {
            const int row = g * 64 + j;
            const float sc = (g == 2) ? SN : SRZ;
#pragma unroll
            for (int q = 0; q < 2; ++q) {
                const float* p = Whh0 + row * 64 + q * 32 + lq * 8;
                bf16x8 vh, vl;
#pragma unroll
                for (int i = 0; i < 8; ++i) {
                    float f = p[i] * sc;
                    short hs = f2bf(f);
                    vh[i] = hs; vl[i] = f2bf(f - bf2f(hs));
                }
                whi[g][q] = vh; wlo[g][q] = vl;
            }
        }
        const float wi_r0 = SRZ * Wih0[j * 2 + 0],         wi_r1 = SRZ * Wih0[j * 2 + 1];
        const float wi_z0 = SRZ * Wih0[(64 + j) * 2 + 0],  wi_z1 = SRZ * Wih0[(64 + j) * 2 + 1];
        const float wi_n0 = SN  * Wih0[(128 + j) * 2 + 0], wi_n1 = SN  * Wih0[(128 + j) * 2 + 1];
        // biases folded into accumulator init (same value in all 4 C regs)
        const float cb[3] = { SRZ * (bih0[j] + bhh0[j]),
                              SRZ * (bih0[64 + j] + bhh0[64 + j]),
                              SN  * bhh0[128 + j] };
        const float bi0_n = SN * bih0[128 + j];

        float h0r[2] = {0.f, 0.f};
        // rows lq*2 and lq*2+1 are contiguous in x: one f32x4 = {x0r0,x1r0,x0r1,x1r1}
        const float* xp = x + (size_t)(b0 + lq * 2) * 2;
        f32x4 xc = *(const f32x4*)xp;
        f32x4 xnb = xc;

        for (int t = 0; t <= TSTEPS; ++t) {
            const int pr = t & 1, pw = pr ^ 1;
            bf16x8 a00 = *(const bf16x8*)&h0A[pr][aoff];
            bf16x8 a01 = *(const bf16x8*)&h0A[pr][aoff + 32];

            if (t + 1 < TSTEPS) {
                xp += (size_t)BATCH * 2;
                xnb = *(const f32x4*)xp;
            }

            f32x4 hg0[3];
#pragma unroll
            for (int g = 0; g < 3; ++g) {
                const f32x4 ci = {cb[g], cb[g], cb[g], cb[g]};
                f32x4 c;
                c = __builtin_amdgcn_mfma_f32_16x16x32_bf16(a00, whi[g][0], ci, 0, 0, 0);
                c = __builtin_amdgcn_mfma_f32_16x16x32_bf16(a01, whi[g][1], c, 0, 0, 0);
                c = __builtin_amdgcn_mfma_f32_16x16x32_bf16(a00, wlo[g][0], c, 0, 0, 0);
                hg0[g] = __builtin_amdgcn_mfma_f32_16x16x32_bf16(a01, wlo[g][1], c, 0, 0, 0);
            }

            if (t < TSTEPS) {
#pragma unroll
                for (int i = 0; i < 2; ++i) {
                    const float x0 = xc[i * 2], x1 = xc[i * 2 + 1];
                    const float gr = fmaf(wi_r0, x0, fmaf(wi_r1, x1, hg0[0][i]));
                    const float gz = fmaf(wi_z0, x0, fmaf(wi_z1, x1, hg0[1][i]));
                    const float gn = fmaf(wi_n0, x0, fmaf(wi_n1, x1, bi0_n));
                    const float r = sig_pre(gr);
                    const float z = sig_pre(gz);
                    const float n = tanh_pre(fmaf(r, hg0[2][i], gn));
                    const float h = fmaf(z, h0r[i] - n, n);
                    h0r[i] = h;
                    h0A[pw][(lq * 4 + i) * 72 + j] = f2bf(h);
                }
            }
            xc = xnb;
            __syncthreads();   // barrier 1..513
        }

        const float wp0 = Wp[j];
#pragma unroll
        for (int i = 0; i < 2; ++i)
            Pf[lq * 2 + i][j] = wp0 * h0r[i];
        __syncthreads();       // barrier 514
        __syncthreads();       // barrier 515
    } else {
        // ================= layer-1 waves =================
        bf16x8 w1hi[3][2], w1lo[3][2], w2hi[3][2], w2lo[3][2];
#pragma unroll
        for (int g = 0; g < 3; ++g) {
            const int row = g * 64 + j;
            const float sc = (g == 2) ? SN : SRZ;
#pragma unroll
            for (int q = 0; q < 2; ++q) {
                const float* p1 = Wih1 + row * 64 + q * 32 + lq * 8;
                const float* p2 = Whh1 + row * 64 + q * 32 + lq * 8;
                bf16x8 v1h, v1l, v2h, v2l;
#pragma unroll
                for (int i = 0; i < 8; ++i) {
                    float f1 = p1[i] * sc, f2 = p2[i] * sc;
                    short s1 = f2bf(f1), s2 = f2bf(f2);
                    v1h[i] = s1; v1l[i] = f2bf(f1 - bf2f(s1));
                    v2h[i] = s2; v2l[i] = f2bf(f2 - bf2f(s2));
                }
                w1hi[g][q] = v1h; w1lo[g][q] = v1l;
                w2hi[g][q] = v2h; w2lo[g][q] = v2l;
            }
        }
        // fold all biases into the xg1 accumulator chain
        const float cb[3] = { SRZ * (bih1[j] + bhh1[j]),
                              SRZ * (bih1[64 + j] + bhh1[64 + j]),
                              SN  * bih1[128 + j] };
        const float bh1_n = SN * bhh1[128 + j];

        float h1r[2] = {0.f, 0.f};

        for (int t = 0; t <= TSTEPS; ++t) {
            const int pr = t & 1, pw = pr ^ 1;
            bf16x8 a00 = *(const bf16x8*)&h0A[pr][aoff];
            bf16x8 a01 = *(const bf16x8*)&h0A[pr][aoff + 32];
            bf16x8 a10 = *(const bf16x8*)&h1A[pr][aoff];
            bf16x8 a11 = *(const bf16x8*)&h1A[pr][aoff + 32];

            f32x4 xg1[3], hg1[3];
#pragma unroll
            for (int g = 0; g < 3; ++g) {
                const f32x4 z4 = {0.f, 0.f, 0.f, 0.f};
                const f32x4 ci = {cb[g], cb[g], cb[g], cb[g]};
                f32x4 d;
                d = __builtin_amdgcn_mfma_f32_16x16x32_bf16(a00, w1hi[g][0], ci, 0, 0, 0);
                d = __builtin_amdgcn_mfma_f32_16x16x32_bf16(a01, w1hi[g][1], d, 0, 0, 0);
                d = __builtin_amdgcn_mfma_f32_16x16x32_bf16(a00, w1lo[g][0], d, 0, 0, 0);
                xg1[g] = __builtin_amdgcn_mfma_f32_16x16x32_bf16(a01, w1lo[g][1], d, 0, 0, 0);
                f32x4 e;
                e = __builtin_amdgcn_mfma_f32_16x16x32_bf16(a10, w2hi[g][0], z4, 0, 0, 0);
                e = __builtin_amdgcn_mfma_f32_16x16x32_bf16(a11, w2hi[g][1], e, 0, 0, 0);
                e = __builtin_amdgcn_mfma_f32_16x16x32_bf16(a10, w2lo[g][0], e, 0, 0, 0);
                hg1[g] = __builtin_amdgcn_mfma_f32_16x16x32_bf16(a11, w2lo[g][1], e, 0, 0, 0);
            }

            if (t > 0) {
#pragma unroll
                for (int i = 0; i < 2; ++i) {
                    const float r = sig_pre(xg1[0][i] + hg1[0][i]);
                    const float z = sig_pre(xg1[1][i] + hg1[1][i]);
                    const float n = tanh_pre(fmaf(r, fmaf(1.0f, hg1[2][i], bh1_n), xg1[2][i]));
                    const float h = fmaf(z, h1r[i] - n, n);
                    h1r[i] = h;
                    h1A[pw][(lq * 4 + i) * 72 + j] = f2bf(h);
                }
            }
            __syncthreads();   // barrier 1..513
        }

        __syncthreads();       // barrier 514 (Pf written by L0 waves)
        const float wp1 = Wp[64 + j];
#pragma unroll
        for (int i = 0; i < 2; ++i)
            Pf[lq * 2 + i][j] += wp1 * h1r[i];
        __syncthreads();       // barrier 515
    }

    // ---- final reduce: out[b] = sum_j Pf[row][j] + bp ----
    if (tid < 8) {
        float s = bp[0];
#pragma unroll 8
        for (int k = 0; k < 64; ++k) s += Pf[tid][k];
        out[b0 + tid] = s;
    }
}

extern "C" void kernel_launch(void* const* d_in, const int* in_sizes, int n_in,
                              void* d_out, int out_size, void* d_ws, size_t ws_size,
                              hipStream_t stream) {
    (void)in_sizes; (void)n_in; (void)out_size; (void)d_ws; (void)ws_size;
    gru_fused<<<dim3(BATCH / 8), dim3(512), 0, stream>>>(
        (const float*)d_in[0], (const float*)d_in[1], (const float*)d_in[2],
        (const float*)d_in[3], (const float*)d_in[4], (const float*)d_in[5],
        (const float*)d_in[6], (const float*)d_in[7], (const float*)d_in[8],
        (const float*)d_in[9], (const float*)d_in[10], (float*)d_out);
}

// Round 8
// 408.469 us; speedup vs baseline: 1.6500x; 1.4003x over previous
//
#include <hip/hip_runtime.h>
#include <stdint.h>

#define TSTEPS 512
#define BATCH  4096
// R8: 512 blocks x 512 threads, 8 rows/block, wave-specialized
// (waves 0-3: hg0+EW0, waves 4-7: xg1+hg1+EW1), one barrier/step.
// Weights single-bf16 (hi/lo split dropped): halves MFMA count and cuts
// ~48 VGPRs so the true unified VGPR+AGPR footprint fits under 128
// -> 2 blocks/CU = 4 waves/SIMD truly co-resident (R7 failed: ~140 regs).
// __launch_bounds__(512,4) caps at 128; natural usage ~103 -> no spill
// (watch WRITE_SIZE for the R3/R6 spill signature).

typedef __attribute__((ext_vector_type(8))) short bf16x8;
typedef __attribute__((ext_vector_type(4))) float f32x4;

#define SRZ (-1.4426950408889634f)   /* -log2(e): r,z gates */
#define SN  ( 2.8853900817779268f)   /* 2*log2(e): n gate   */

__device__ __forceinline__ short f2bf(float f) {
    uint32_t u = __float_as_uint(f);
    uint32_t r = (u + 0x7fffu + ((u >> 16) & 1u)) >> 16;
    return (short)r;
}
__device__ __forceinline__ float fast_rcp(float x) { return __builtin_amdgcn_rcpf(x); }
#if __has_builtin(__builtin_amdgcn_exp2f)
__device__ __forceinline__ float exp2_fast(float x) { return __builtin_amdgcn_exp2f(x); }
#else
__device__ __forceinline__ float exp2_fast(float x) { return __expf(x * 0.6931471805599453f); }
#endif
__device__ __forceinline__ float sig_pre(float y) { return fast_rcp(1.0f + exp2_fast(y)); }
__device__ __forceinline__ float tanh_pre(float y) { return 1.0f - 2.0f * fast_rcp(1.0f + exp2_fast(y)); }

__global__ __launch_bounds__(512, 4) void gru_fused(
    const float* __restrict__ x,     // [T,B,2]
    const float* __restrict__ Wih0,  // [192,2]
    const float* __restrict__ Whh0,  // [192,64]
    const float* __restrict__ bih0,  // [192]
    const float* __restrict__ bhh0,  // [192]
    const float* __restrict__ Wih1,  // [192,64]
    const float* __restrict__ Whh1,  // [192,64]
    const float* __restrict__ bih1,  // [192]
    const float* __restrict__ bhh1,  // [192]
    const float* __restrict__ Wp,    // [128]
    const float* __restrict__ bp,    // [1]
    float* __restrict__ out)         // [B]
{
    const int tid  = threadIdx.x;
    const int wv   = tid >> 6;      // wave 0..7
    const int isL0 = (wv < 4);
    const int w4   = wv & 3;
    const int l    = tid & 63;
    const int lm   = l & 15;        // A row m / n-col within tile
    const int lq   = l >> 4;        // quad
    const int b0   = blockIdx.x * 8;
    const int j    = w4 * 16 + lm;  // hidden index this lane owns

    // Batch row r (0..7) at MFMA row m = lq*4 + i (r = lq*2+i, i in {0,1});
    // rows with m&3 >= 2 stay zero forever.
    __shared__ short h0A[2][16 * 72];
    __shared__ short h1A[2][16 * 72];
    __shared__ float Pf[8][64];

    for (int idx = tid; idx < 2 * 16 * 72; idx += 512) {
        ((short*)h0A)[idx] = 0;
        ((short*)h1A)[idx] = 0;
    }
    __syncthreads();

    const int aoff = lm * 72 + lq * 8;  // shorts; +32 for K-half 1

    if (isL0) {
        // ================= layer-0 waves =================
        bf16x8 w0[3][2];   // Whh0, gate-prescaled, single bf16
#pragma unroll
        for (int g = 0; g < 3; ++g) {
            const int row = g * 64 + j;
            const float sc = (g == 2) ? SN : SRZ;
#pragma unroll
            for (int q = 0; q < 2; ++q) {
                const float* p = Whh0 + row * 64 + q * 32 + lq * 8;
                bf16x8 vh;
#pragma unroll
                for (int i = 0; i < 8; ++i) vh[i] = f2bf(p[i] * sc);
                w0[g][q] = vh;
            }
        }
        const float wi_r0 = SRZ * Wih0[j * 2 + 0],         wi_r1 = SRZ * Wih0[j * 2 + 1];
        const float wi_z0 = SRZ * Wih0[(64 + j) * 2 + 0],  wi_z1 = SRZ * Wih0[(64 + j) * 2 + 1];
        const float wi_n0 = SN  * Wih0[(128 + j) * 2 + 0], wi_n1 = SN  * Wih0[(128 + j) * 2 + 1];
        const float cb[3] = { SRZ * (bih0[j] + bhh0[j]),
                              SRZ * (bih0[64 + j] + bhh0[64 + j]),
                              SN  * bhh0[128 + j] };
        const float bi0_n = SN * bih0[128 + j];

        float h0r[2] = {0.f, 0.f};
        const float* xp = x + (size_t)(b0 + lq * 2) * 2;
        f32x4 xc = *(const f32x4*)xp;
        f32x4 xnb = xc;

        for (int t = 0; t <= TSTEPS; ++t) {
            const int pr = t & 1, pw = pr ^ 1;
            bf16x8 a00 = *(const bf16x8*)&h0A[pr][aoff];
            bf16x8 a01 = *(const bf16x8*)&h0A[pr][aoff + 32];

            if (t + 1 < TSTEPS) {
                xp += (size_t)BATCH * 2;
                xnb = *(const f32x4*)xp;
            }

            f32x4 hg0[3];
#pragma unroll
            for (int g = 0; g < 3; ++g) {
                const f32x4 ci = {cb[g], cb[g], cb[g], cb[g]};
                f32x4 c;
                c = __builtin_amdgcn_mfma_f32_16x16x32_bf16(a00, w0[g][0], ci, 0, 0, 0);
                hg0[g] = __builtin_amdgcn_mfma_f32_16x16x32_bf16(a01, w0[g][1], c, 0, 0, 0);
            }

            if (t < TSTEPS) {
#pragma unroll
                for (int i = 0; i < 2; ++i) {
                    const float x0 = xc[i * 2], x1 = xc[i * 2 + 1];
                    const float gr = fmaf(wi_r0, x0, fmaf(wi_r1, x1, hg0[0][i]));
                    const float gz = fmaf(wi_z0, x0, fmaf(wi_z1, x1, hg0[1][i]));
                    const float gn = fmaf(wi_n0, x0, fmaf(wi_n1, x1, bi0_n));
                    const float r = sig_pre(gr);
                    const float z = sig_pre(gz);
                    const float n = tanh_pre(fmaf(r, hg0[2][i], gn));
                    const float h = fmaf(z, h0r[i] - n, n);
                    h0r[i] = h;
                    h0A[pw][(lq * 4 + i) * 72 + j] = f2bf(h);
                }
            }
            xc = xnb;
            __syncthreads();   // barrier 1..513
        }

        const float wp0 = Wp[j];
#pragma unroll
        for (int i = 0; i < 2; ++i)
            Pf[lq * 2 + i][j] = wp0 * h0r[i];
        __syncthreads();       // barrier 514
        __syncthreads();       // barrier 515
    } else {
        // ================= layer-1 waves =================
        bf16x8 w1[3][2], w2[3][2];   // Wih1, Whh1, gate-prescaled, single bf16
#pragma unroll
        for (int g = 0; g < 3; ++g) {
            const int row = g * 64 + j;
            const float sc = (g == 2) ? SN : SRZ;
#pragma unroll
            for (int q = 0; q < 2; ++q) {
                const float* p1 = Wih1 + row * 64 + q * 32 + lq * 8;
                const float* p2 = Whh1 + row * 64 + q * 32 + lq * 8;
                bf16x8 v1, v2;
#pragma unroll
                for (int i = 0; i < 8; ++i) {
                    v1[i] = f2bf(p1[i] * sc);
                    v2[i] = f2bf(p2[i] * sc);
                }
                w1[g][q] = v1; w2[g][q] = v2;
            }
        }
        const float cb[3] = { SRZ * (bih1[j] + bhh1[j]),
                              SRZ * (bih1[64 + j] + bhh1[64 + j]),
                              SN  * bih1[128 + j] };
        const float bh1_n = SN * bhh1[128 + j];

        float h1r[2] = {0.f, 0.f};

        for (int t = 0; t <= TSTEPS; ++t) {
            const int pr = t & 1, pw = pr ^ 1;
            bf16x8 a00 = *(const bf16x8*)&h0A[pr][aoff];
            bf16x8 a01 = *(const bf16x8*)&h0A[pr][aoff + 32];
            bf16x8 a10 = *(const bf16x8*)&h1A[pr][aoff];
            bf16x8 a11 = *(const bf16x8*)&h1A[pr][aoff + 32];

            f32x4 xg1[3], hg1[3];
#pragma unroll
            for (int g = 0; g < 3; ++g) {
                const f32x4 z4 = {0.f, 0.f, 0.f, 0.f};
                const f32x4 ci = {cb[g], cb[g], cb[g], cb[g]};
                f32x4 d;
                d = __builtin_amdgcn_mfma_f32_16x16x32_bf16(a00, w1[g][0], ci, 0, 0, 0);
                xg1[g] = __builtin_amdgcn_mfma_f32_16x16x32_bf16(a01, w1[g][1], d, 0, 0, 0);
                f32x4 e;
                e = __builtin_amdgcn_mfma_f32_16x16x32_bf16(a10, w2[g][0], z4, 0, 0, 0);
                hg1[g] = __builtin_amdgcn_mfma_f32_16x16x32_bf16(a11, w2[g][1], e, 0, 0, 0);
            }

            if (t > 0) {
#pragma unroll
                for (int i = 0; i < 2; ++i) {
                    const float r = sig_pre(xg1[0][i] + hg1[0][i]);
                    const float z = sig_pre(xg1[1][i] + hg1[1][i]);
                    const float n = tanh_pre(fmaf(r, hg1[2][i] + bh1_n, xg1[2][i]));
                    const float h = fmaf(z, h1r[i] - n, n);
                    h1r[i] = h;
                    h1A[pw][(lq * 4 + i) * 72 + j] = f2bf(h);
                }
            }
            __syncthreads();   // barrier 1..513
        }

        __syncthreads();       // barrier 514 (Pf written by L0 waves)
        const float wp1 = Wp[64 + j];
#pragma unroll
        for (int i = 0; i < 2; ++i)
            Pf[lq * 2 + i][j] += wp1 * h1r[i];
        __syncthreads();       // barrier 515
    }

    // ---- final reduce: out[b] = sum_j Pf[row][j] + bp ----
    if (tid < 8) {
        float s = bp[0];
#pragma unroll 8
        for (int k = 0; k < 64; ++k) s += Pf[tid][k];
        out[b0 + tid] = s;
    }
}

extern "C" void kernel_launch(void* const* d_in, const int* in_sizes, int n_in,
                              void* d_out, int out_size, void* d_ws, size_t ws_size,
                              hipStream_t stream) {
    (void)in_sizes; (void)n_in; (void)out_size; (void)d_ws; (void)ws_size;
    gru_fused<<<dim3(BATCH / 8), dim3(512), 0, stream>>>(
        (const float*)d_in[0], (const float*)d_in[1], (const float*)d_in[2],
        (const float*)d_in[3], (const float*)d_in[4], (const float*)d_in[5],
        (const float*)d_in[6], (const float*)d_in[7], (const float*)d_in[8],
        (const float*)d_in[9], (const float*)d_in[10], (float*)d_out);
}